// Round 6
// baseline (2135.615 us; speedup 1.0000x reference)
//
#include <hip/hip_runtime.h>
#include <math.h>

// RealNVP, 8 layers, B=262144, H=128, scalar coupling input.
// Exact piecewise-linear collapse (verified R4). One kernel per layer:
// hist -> ticket(last block does single-block FIN) -> flag spin(acquire) ->
// apply -> ticket(last block does single-block PREP of next layer).
// cg::grid.sync (R5) cost ~50us/sync w/ full cache thrash; hand-rolled
// agent-scope ticket/flag + s_sleep spin avoids it. Kernel boundaries
// provide coherence for cross-kernel data (as in R1-R4); intra-kernel
// flag-crossing data (seg tables, parts) is write-once + threadfence.

#define BN_ 262144
#define H_ 128
#define NBINS 129
#define NBLK 256
#define NTHR 1024

// ws layout (float offsets)
#define OFF_X0   0
#define OFF_X1   BN_
#define OFF_SL   (2*BN_)
#define OFF_PART (3*BN_)             // double2[256] = 1024 floats (16B aligned)
#define OFF_BIN  (3*BN_+1024)        // 512: cnt[0..131], sx[+132], sxx[+264]
#define OFF_TS   (3*BN_+1536)        // 128 sorted breakpoints
#define OFF_S    (3*BN_+1664)        // float2 S[129][128] = 33024 floats
#define OFF_XS   (OFF_S+33024)       // 129*132 crossings
#define OFF_SEG  (OFF_XS+17028)      // float4 seg[129][132] (16B aligned)
#define OFF_REF  (OFF_SEG+68112)     // 129*132
#define OFF_CNT  (OFF_REF+17028)     // 132 ints
#define OFF_TICK (OFF_CNT+132)       // 16 ints (2 per layer)
#define OFF_FLAG (OFF_TICK+16)       // 8 ints

struct SmemPrep {
    float v2L[H_*129];               // padded rows: bank-safe column gathers
    float sA[H_], sC[H_], sT[H_];
    int order[H_];
    double red[32];
};
struct SmemHist { float lts[H_]; float lb[4*396]; };
struct SmemFin {
    double meanD[H_], RD[H_];
    float xc[16*H_], xs[16*H_];      // per-wave scratch rows
    double2 dW[16*H_];
};
struct SmemApply { double red[32]; };
union Smem { SmemPrep p; SmemHist h; SmemFin f; SmemApply a; };

__device__ __forceinline__ double bsum(double v, double* red, int tid) {
    for (int o = 32; o; o >>= 1) v += __shfl_down(v, o);
    __syncthreads();
    if ((tid & 63) == 0) red[tid >> 6] = v;
    __syncthreads();
    double r = 0.0;
    #pragma unroll
    for (int w = 0; w < 16; w++) r += red[w];
    return r;
}

// Whole-block prep of layer l's tables (ts sorted, S[k][i]) from xin stats.
__device__ void prep_layer(int l, double Ssum, double SSq,
    const float* __restrict__ v1, const float* __restrict__ g1,
    const float* __restrict__ bn1g, const float* __restrict__ bn1b,
    const float* __restrict__ v2, const float* __restrict__ g2,
    const float* __restrict__ b2, float* ws, SmemPrep* sp, int tid) {
    double mx = Ssum * (1.0 / BN_);
    double vx = fmax(SSq * (1.0 / BN_) - mx * mx, 0.0);
    if (tid < H_) {
        int j = tid;
        float g1v = g1[l*H_ + j];
        float w1 = (v1[l*H_ + j] >= 0.f) ? g1v : -g1v;
        double rr = 1.0 / sqrt(vx * (double)g1v * g1v + 1e-5);
        float a = (float)((double)w1 * rr * bn1g[l*H_ + j]);
        float c = (float)((double)bn1b[l*H_ + j] - mx * a);
        float tj = (a != 0.f) ? (float)(-(double)c / a) : INFINITY;
        sp->sA[j] = a; sp->sC[j] = c; sp->sT[j] = tj;
    }
    for (int e = tid; e < H_*H_; e += NTHR)
        sp->v2L[(e >> 7)*129 + (e & 127)] = v2[l*H_*H_ + e];
    __syncthreads();
    if (tid < H_) {
        int j = tid; float tj = sp->sT[j];
        int rk = 0;
        for (int q = 0; q < H_; q++) {
            float tq = sp->sT[q];
            rk += ((tq < tj) || (tq == tj && q < j)) ? 1 : 0;
        }
        sp->order[rk] = j;
        ws[OFF_TS + rk] = tj;
    }
    __syncthreads();
    if (tid < H_) {
        int i = tid;
        double n2 = 0.0;
        for (int j = 0; j < H_; j++) { double v = sp->v2L[i*129 + j]; n2 += v * v; }
        double wsc = (double)g2[l*H_ + i] / sqrt(n2);
        double base1 = 0.0, base0 = 0.0;
        for (int j = 0; j < H_; j++) {
            float a = sp->sA[j], c = sp->sC[j];
            if ((a < 0.f) || (a == 0.f && c > 0.f)) {
                double w = wsc * sp->v2L[i*129 + j];
                base1 += w * a; base0 += w * c;
            }
        }
        float2* S = (float2*)(ws + OFF_S);
        double acc1 = base1, acc0 = base0 + (double)b2[l*H_ + i];
        S[i] = make_float2((float)acc1, (float)acc0);
        for (int k = 1; k < NBINS; k++) {
            int jj = sp->order[k - 1];
            float aa = sp->sA[jj], cc = sp->sC[jj];
            if (aa != 0.f) {
                double sg = (aa > 0.f) ? 1.0 : -1.0;
                double wj = wsc * sp->v2L[i*129 + jj];
                acc1 += sg * wj * aa; acc0 += sg * wj * cc;
            }
            S[k*H_ + i] = make_float2((float)acc1, (float)acc0);
        }
    }
    if (tid < 512) ws[OFF_BIN + tid] = 0.f;   // bins for next layer's hist
}

// Single-block FIN: exact BN2 stats + per-interval segment tables.
// Intervals distributed one per wave; wave-local LDS scratch, no cross-wave
// barriers inside the loop.
__device__ void fin_layer(int l,
    const float* __restrict__ bn2g, const float* __restrict__ bn2b,
    const float* __restrict__ wf, const float* __restrict__ bf,
    float* ws, SmemFin* sf, int tid) {
    const float2* S = (const float2*)(ws + OFF_S);
    const float* bins = ws + OFF_BIN;
    const float* ts = ws + OFF_TS;
    if (tid < H_) {
        int i = tid;
        double M = 0.0, E = 0.0;
        for (int kk = 0; kk < NBINS; kk++) {
            float2 s = S[kk*H_ + i];
            double cn = bins[kk], sx = bins[132 + kk], sxx = bins[264 + kk];
            M += (double)s.x * sx + (double)s.y * cn;
            E += (double)s.x * ((double)s.x * sxx + 2.0 * s.y * sx) + (double)s.y * s.y * cn;
        }
        double mean = M * (1.0 / BN_);
        double var = fmax(E * (1.0 / BN_) - mean * mean, 0.0);
        sf->meanD[i] = mean;
        sf->RD[i] = (double)bn2g[l*H_ + i] / sqrt(var + 1e-5);
    }
    __syncthreads();
    int wv = tid >> 6, lane = tid & 63;
    float* xcW = sf->xc + wv * H_;
    float* xsW = sf->xs + wv * H_;
    double2* dW = sf->dW + wv * H_;
    for (int k = wv; k < NBINS; k += 16) {
        float lo_ = (k == 0) ? -3.0e38f : ts[k - 1];
        float hi_ = (k == NBINS - 1) ? 3.0e38f : ts[k];
        float F1v[2], F0v[2], xcv[2], wfsv[2], wftv[2];
        bool actv[2], hasv[2];
        #pragma unroll
        for (int uu = 0; uu < 2; uu++) {
            int u = 2*lane + uu;
            float2 sk = S[k*H_ + u];
            double R = sf->RD[u], mean = sf->meanD[u];
            float F1 = (float)((double)sk.x * R);
            float F0 = (float)(((double)sk.y - mean) * R + bn2b[l*H_ + u]);
            double hlo = (double)F1 * lo_ + F0;
            bool act = (k == 0) ? ((F1 < 0.f) || (F1 == 0.f && F0 > 0.f))
                                : ((hlo > 0.0) || (hlo == 0.0 && F1 > 0.f));
            bool has = false; float xc = INFINITY;
            if (F1 != 0.f) {
                double td = -(double)F0 / F1;
                if (td > lo_ && td < hi_) { has = true; xc = (float)td; }
            }
            F1v[uu]=F1; F0v[uu]=F0; xcv[uu]=xc; actv[uu]=act; hasv[uu]=has;
            wfsv[uu] = wf[l*2*H_ + u]; wftv[uu] = wf[l*2*H_ + H_ + u];
            xcW[u] = xc;
        }
        int cnt = __popcll(__ballot(hasv[0])) + __popcll(__ballot(hasv[1]));
        #pragma unroll
        for (int uu = 0; uu < 2; uu++) {
            int u = 2*lane + uu; float xc = xcv[uu];
            int r = 0;
            for (int q = 0; q < H_; q++) {
                float key = xcW[q];
                r += ((key < xc) || (key == xc && q < u)) ? 1 : 0;
            }
            if (hasv[uu]) {
                double sg = (F1v[uu] > 0.f) ? 1.0 : -1.0;
                dW[r] = make_double2(sg * (double)wfsv[uu] * F1v[uu],
                                     sg * (double)wftv[uu] * F1v[uu]);
                xsW[r] = xc;
                ws[OFF_XS + k*132 + r] = xc;
            }
        }
        float ref0 = (k == 0) ? ((cnt > 0) ? xsW[0] : ts[0]) : ts[k - 1];
        double as = 0, at = 0, vs = 0, vt = 0;
        #pragma unroll
        for (int uu = 0; uu < 2; uu++) {
            float hr = fmaxf(fmaf(F1v[uu], ref0, F0v[uu]), 0.f);
            vs += (double)wfsv[uu] * hr; vt += (double)wftv[uu] * hr;
            if (actv[uu]) { as += (double)wfsv[uu] * F1v[uu]; at += (double)wftv[uu] * F1v[uu]; }
        }
        for (int o = 32; o; o >>= 1) {
            as += __shfl_down(as, o); at += __shfl_down(at, o);
            vs += __shfl_down(vs, o); vt += __shfl_down(vt, o);
        }
        if (lane == 0) {
            float4* seg = (float4*)(ws + OFF_SEG) + k * 132;
            float* refk = ws + OFF_REF + k * 132;
            double As = as, At = at, Vs = vs + bf[2*l], Vt = vt + bf[2*l + 1];
            float ref = ref0;
            seg[0] = make_float4((float)As, (float)Vs, (float)At, (float)Vt);
            refk[0] = ref;
            for (int r2 = 0; r2 < cnt; r2++) {
                float xr = xsW[r2];
                Vs += As * (double)(xr - ref);
                Vt += At * (double)(xr - ref);
                As += dW[r2].x; At += dW[r2].y;
                ref = xr;
                seg[r2 + 1] = make_float4((float)As, (float)Vs, (float)At, (float)Vt);
                refk[r2 + 1] = ref;
            }
            ((int*)ws)[OFF_CNT + k] = cnt;
        }
    }
    __syncthreads();
}

__global__ __launch_bounds__(NTHR) void k_init0(const float* __restrict__ x, float* ws) {
    int tid = threadIdx.x, blk = blockIdx.x;
    int b = blk * NTHR + tid;
    float2 xv = ((const float2*)x)[b];
    ws[OFF_X0 + b] = xv.x;
    ws[OFF_X1 + b] = xv.y;
    __shared__ double red[32];
    double s1 = xv.y, s2 = (double)xv.y * xv.y;
    for (int o = 32; o; o >>= 1) { s1 += __shfl_down(s1, o); s2 += __shfl_down(s2, o); }
    if ((tid & 63) == 0) { red[tid >> 6] = s1; red[16 + (tid >> 6)] = s2; }
    __syncthreads();
    if (tid == 0) {
        double aa = 0, cc = 0;
        for (int w = 0; w < 16; w++) { aa += red[w]; cc += red[16 + w]; }
        ((double2*)(ws + OFF_PART))[blk] = make_double2(aa, cc);
    }
    if (blk == 0) {
        if (tid < 512) ws[OFF_BIN + tid] = 0.f;
        if (tid < 24) ((int*)ws)[OFF_TICK + tid] = 0;  // 16 ticks + 8 flags
    }
}

__global__ __launch_bounds__(NTHR, 1) void k_prep0(
    const float* __restrict__ v1, const float* __restrict__ g1,
    const float* __restrict__ bn1g, const float* __restrict__ bn1b,
    const float* __restrict__ v2, const float* __restrict__ g2,
    const float* __restrict__ b2, float* ws) {
    __shared__ Smem sm;
    int tid = threadIdx.x;
    const double2* parts = (const double2*)(ws + OFF_PART);
    double p1 = 0, p2 = 0;
    if (tid < NBLK) { double2 p = parts[tid]; p1 = p.x; p2 = p.y; }
    double Ssum = bsum(p1, sm.p.red, tid);
    double SSq  = bsum(p2, sm.p.red, tid);
    prep_layer(0, Ssum, SSq, v1, g1, bn1g, bn1b, v2, g2, b2, ws, &sm.p, tid);
}

__global__ __launch_bounds__(NTHR, 1) void k_layer(
    const float* __restrict__ v1, const float* __restrict__ g1,
    const float* __restrict__ bn1g, const float* __restrict__ bn1b,
    const float* __restrict__ v2, const float* __restrict__ g2,
    const float* __restrict__ b2,
    const float* __restrict__ bn2g, const float* __restrict__ bn2b,
    const float* __restrict__ wf, const float* __restrict__ bf,
    float* ws, float* out, int l) {
    __shared__ Smem sm;
    __shared__ int sLast;
    const int tid = threadIdx.x, blk = blockIdx.x;
    const int b = blk * NTHR + tid;
    const int rev = ((l & 1) == 0) ? 1 : 0;
    const int last = (l == 7);
    float x0v = ws[OFF_X0 + b], x1v = ws[OFF_X1 + b];
    float xin = rev ? x1v : x0v;

    // ---- HIST ----
    if (tid < H_) sm.h.lts[tid] = ws[OFF_TS + tid];
    for (int e = tid; e < 4*396; e += NTHR) sm.h.lb[e] = 0.f;
    __syncthreads();
    int lo = 0, hi = H_;
    while (lo < hi) { int mid = (lo + hi) >> 1; if (sm.h.lts[mid] < xin) lo = mid + 1; else hi = mid; }
    const int bin = lo;
    float* lbr = sm.h.lb + ((tid >> 6) & 3) * 396;
    atomicAdd(&lbr[bin], 1.f);
    atomicAdd(&lbr[132 + bin], xin);
    atomicAdd(&lbr[264 + bin], xin * xin);
    __syncthreads();
    for (int e = tid; e < 396; e += NTHR) {
        float v = sm.h.lb[e] + sm.h.lb[396 + e] + sm.h.lb[792 + e] + sm.h.lb[1188 + e];
        atomicAdd(&ws[OFF_BIN + e], v);
    }
    __syncthreads();   // drains block's atomics (vmcnt) before ticket
    if (tid == 0) {
        int old = __hip_atomic_fetch_add((int*)ws + OFF_TICK + 2*l, 1,
                                         __ATOMIC_ACQ_REL, __HIP_MEMORY_SCOPE_AGENT);
        sLast = (old == NBLK - 1) ? 1 : 0;
    }
    __syncthreads();
    if (sLast) {
        fin_layer(l, bn2g, bn2b, wf, bf, ws, &sm.f, tid);
        if (tid == 0) {
            __threadfence();
            __hip_atomic_store((int*)ws + OFF_FLAG + l, 1,
                               __ATOMIC_RELEASE, __HIP_MEMORY_SCOPE_AGENT);
        }
    } else if (tid == 0) {
        while (__hip_atomic_load((int*)ws + OFF_FLAG + l,
                                 __ATOMIC_ACQUIRE, __HIP_MEMORY_SCOPE_AGENT) == 0)
            __builtin_amdgcn_s_sleep(8);
    }
    __syncthreads();

    // ---- APPLY ----
    float xo = rev ? x0v : x1v;
    int cnt = ((const int*)ws)[OFF_CNT + bin];
    const float* xsk = ws + OFF_XS + bin * 132;
    int r = 0;
    while (r < cnt && xin > xsk[r]) ++r;
    float4 rec = ((const float4*)(ws + OFF_SEG))[bin * 132 + r];
    float ref = ws[OFF_REF + bin * 132 + r];
    float dx = xin - ref;
    float st_s = fmaf(rec.x, dx, rec.y);
    float st_t = fmaf(rec.z, dx, rec.w);
    float s = tanhf(st_s);
    float y = expf(s) * xo + st_t;
    float sl = ((l == 0) ? 0.f : ws[OFF_SL + b]) + s;

    if (!last) {
        if (rev) ws[OFF_X0 + b] = y; else ws[OFF_X1 + b] = y;
        ws[OFF_SL + b] = sl;
        double s1 = y, s2 = (double)y * y;
        for (int o = 32; o; o >>= 1) { s1 += __shfl_down(s1, o); s2 += __shfl_down(s2, o); }
        __syncthreads();   // also drains y/sl stores; protects LDS union reuse
        if ((tid & 63) == 0) { sm.a.red[tid >> 6] = s1; sm.a.red[16 + (tid >> 6)] = s2; }
        __syncthreads();
        if (tid == 0) {
            double aa = 0, cc = 0;
            for (int w = 0; w < 16; w++) { aa += sm.a.red[w]; cc += sm.a.red[16 + w]; }
            ((double2*)(ws + OFF_PART))[blk] = make_double2(aa, cc);
            __threadfence();   // make parts visible cross-XCD before ticket
            int old = __hip_atomic_fetch_add((int*)ws + OFF_TICK + 2*l + 1, 1,
                                             __ATOMIC_ACQ_REL, __HIP_MEMORY_SCOPE_AGENT);
            sLast = (old == NBLK - 1) ? 1 : 0;
        }
        __syncthreads();
        if (sLast) {
            const double2* parts = (const double2*)(ws + OFF_PART);
            double p1 = 0, p2 = 0;
            if (tid < NBLK) { double2 p = parts[tid]; p1 = p.x; p2 = p.y; }
            double Ssum = bsum(p1, sm.p.red, tid);
            double SSq  = bsum(p2, sm.p.red, tid);
            prep_layer(l + 1, Ssum, SSq, v1, g1, bn1g, bn1b, v2, g2, b2, ws, &sm.p, tid);
        }
    } else {
        float z0 = 1.f / (1.f + expf(-x0v));
        float z1 = 1.f / (1.f + expf(-y));
        ((float2*)out)[b] = make_float2(z0, z1);
        out[2*BN_ + b] = sl + logf(z0 * (1.f - z0) + 1e-4f)
                            + logf(z1 * (1.f - z1) + 1e-4f);
    }
}

extern "C" void kernel_launch(void* const* d_in, const int* in_sizes, int n_in,
                              void* d_out, int out_size, void* d_ws, size_t ws_size,
                              hipStream_t stream) {
    const float* x    = (const float*)d_in[0];
    const float* v1   = (const float*)d_in[1];
    const float* g1   = (const float*)d_in[2];
    // d_in[3] = b1: cancels exactly inside BN1, unused.
    const float* bn1g = (const float*)d_in[4];
    const float* bn1b = (const float*)d_in[5];
    const float* v2   = (const float*)d_in[6];
    const float* g2   = (const float*)d_in[7];
    const float* b2   = (const float*)d_in[8];
    const float* bn2g = (const float*)d_in[9];
    const float* bn2b = (const float*)d_in[10];
    const float* wf   = (const float*)d_in[11];
    const float* bf   = (const float*)d_in[12];
    float* ws  = (float*)d_ws;
    float* out = (float*)d_out;

    k_init0<<<NBLK, NTHR, 0, stream>>>(x, ws);
    k_prep0<<<1, NTHR, 0, stream>>>(v1, g1, bn1g, bn1b, v2, g2, b2, ws);
    for (int l = 0; l < 8; l++) {
        k_layer<<<NBLK, NTHR, 0, stream>>>(v1, g1, bn1g, bn1b, v2, g2, b2,
                                           bn2g, bn2b, wf, bf, ws, out, l);
    }
}